// Round 1
// baseline (465.076 us; speedup 1.0000x reference)
//
#include <hip/hip_runtime.h>
#include <hip/hip_bf16.h>

// -------------------- degree / CSR build --------------------

__global__ void hist_kernel(const int* __restrict__ dst, int* __restrict__ cnt, int E) {
    int e = blockIdx.x * 256 + threadIdx.x;
    if (e < E) atomicAdd(&cnt[dst[e]], 1);
}

__global__ void dinv_kernel(const int* __restrict__ cnt, float* __restrict__ dinv, int N) {
    int i = blockIdx.x * 256 + threadIdx.x;
    if (i < N) dinv[i] = rsqrtf((float)cnt[i] + 1.0f);  // +1 for self loop; deg>0 always
}

// exclusive scan of cnt -> rp, 3 phases (N <= 256*256)
__global__ void scan_a(const int* __restrict__ cnt, int* __restrict__ rp,
                       int* __restrict__ partials, int N) {
    __shared__ int sm[256];
    int tx = threadIdx.x;
    int i = blockIdx.x * 256 + tx;
    int v = (i < N) ? cnt[i] : 0;
    sm[tx] = v;
    __syncthreads();
    for (int off = 1; off < 256; off <<= 1) {
        int t = (tx >= off) ? sm[tx - off] : 0;
        __syncthreads();
        sm[tx] += t;
        __syncthreads();
    }
    if (i < N) rp[i] = sm[tx] - v;            // exclusive within block
    if (tx == 255) partials[blockIdx.x] = sm[tx];  // block total
}

__global__ void scan_b(int* __restrict__ partials, int nb) {
    __shared__ int sm[256];
    int tx = threadIdx.x;
    int v = (tx < nb) ? partials[tx] : 0;
    sm[tx] = v;
    __syncthreads();
    for (int off = 1; off < 256; off <<= 1) {
        int t = (tx >= off) ? sm[tx - off] : 0;
        __syncthreads();
        sm[tx] += t;
        __syncthreads();
    }
    if (tx < nb) partials[tx] = sm[tx] - v;   // exclusive
}

__global__ void scan_c(int* __restrict__ rp, const int* __restrict__ partials,
                       int* __restrict__ pos, int N) {
    int i = blockIdx.x * 256 + threadIdx.x;
    if (i < N) {
        int v = rp[i] + partials[blockIdx.x];
        rp[i] = v;
        pos[i] = v;
    }
}

__global__ void place_kernel(const int* __restrict__ src, const int* __restrict__ dst,
                             int* __restrict__ pos, int* __restrict__ col, int E) {
    int e = blockIdx.x * 256 + threadIdx.x;
    if (e < E) {
        int d = dst[e];
        int p = atomicAdd(&pos[d], 1);
        col[p] = src[e];
    }
}

// -------------------- dense GEMM: Y[N,NC] = X[N,128] @ W[128,NC] --------------------
// K fixed at 128. Block = 256 threads, tile = 64 rows.

template <int NC>
__launch_bounds__(256)
__global__ void gemm_k128(const float* __restrict__ X, const float* __restrict__ W,
                          float* __restrict__ Y, int N) {
    constexpr int CG = NC / 4;        // float4 col-groups per row
    constexpr int RPT = CG / 4;       // rows per thread (8 for NC=128, 4 for NC=64)
    constexpr int STRIDE = 132;       // padded LDS row stride (floats) to avoid bank conflicts
    __shared__ float xs[64 * STRIDE];

    int tid = threadIdx.x;
    int r0 = blockIdx.x * 64;
    const float4* X4 = (const float4*)X;

    // stage 64 rows x 128 cols (float4 loads, coalesced)
#pragma unroll
    for (int j = 0; j < 8; ++j) {
        int idx = tid + j * 256;      // 0..2047 float4 slots
        int lr = idx >> 5;            // /32 float4 per row
        int lc = idx & 31;
        int gr = r0 + lr;
        float4 v = make_float4(0.f, 0.f, 0.f, 0.f);
        if (gr < N) v = X4[gr * 32 + lc];
        *(float4*)&xs[lr * STRIDE + lc * 4] = v;
    }
    __syncthreads();

    int cx = tid % CG;
    int ry = tid / CG;

    float4 acc[RPT];
#pragma unroll
    for (int i = 0; i < RPT; ++i) acc[i] = make_float4(0.f, 0.f, 0.f, 0.f);

    const float4* W4 = (const float4*)W;
#pragma unroll 4
    for (int k = 0; k < 128; ++k) {
        float4 wv = W4[k * CG + cx];
#pragma unroll
        for (int i = 0; i < RPT; ++i) {
            float xv = xs[(ry * RPT + i) * STRIDE + k];
            acc[i].x = fmaf(xv, wv.x, acc[i].x);
            acc[i].y = fmaf(xv, wv.y, acc[i].y);
            acc[i].z = fmaf(xv, wv.z, acc[i].z);
            acc[i].w = fmaf(xv, wv.w, acc[i].w);
        }
    }

    float4* Y4 = (float4*)Y;
#pragma unroll
    for (int i = 0; i < RPT; ++i) {
        int row = r0 + ry * RPT + i;
        if (row < N) Y4[row * CG + cx] = acc[i];
    }
}

// -------------------- CSR aggregation: O = dinv .* (A_csr @ (dinv .* T)) + self + bias --------------------

template <int F, bool RELU>
__launch_bounds__(256)
__global__ void agg_csr(const float* __restrict__ T, const float* __restrict__ dinv,
                        const int* __restrict__ rp, const int* __restrict__ cnt,
                        const int* __restrict__ col, const float* __restrict__ bias,
                        float* __restrict__ O, int N) {
    constexpr int TPN = F / 4;        // threads per node (32 for F=128, 16 for F=64)
    constexpr int NPB = 256 / TPN;    // nodes per block
    int tid = threadIdx.x;
    int node = blockIdx.x * NPB + tid / TPN;
    int f4 = tid % TPN;
    if (node >= N) return;

    const float4* T4 = (const float4*)T;
    float di = dinv[node];

    // self loop: dinv[node] * t[node]   (outer dinv[node] applied at the end)
    float4 s = T4[node * TPN + f4];
    s.x *= di; s.y *= di; s.z *= di; s.w *= di;

    int start = rp[node];
    int num = cnt[node];
    for (int k = 0; k < num; ++k) {
        int j = col[start + k];
        float dj = dinv[j];
        float4 v = T4[j * TPN + f4];
        s.x = fmaf(v.x, dj, s.x);
        s.y = fmaf(v.y, dj, s.y);
        s.z = fmaf(v.z, dj, s.z);
        s.w = fmaf(v.w, dj, s.w);
    }

    float4 b = ((const float4*)bias)[f4];
    float4 o;
    o.x = fmaf(s.x, di, b.x);
    o.y = fmaf(s.y, di, b.y);
    o.z = fmaf(s.z, di, b.z);
    o.w = fmaf(s.w, di, b.w);
    if (RELU) {
        o.x = fmaxf(o.x, 0.f);
        o.y = fmaxf(o.y, 0.f);
        o.z = fmaxf(o.z, 0.f);
        o.w = fmaxf(o.w, 0.f);
    }
    ((float4*)O)[node * TPN + f4] = o;
}

// -------------------- decode: logits[e] = dot(z[u], z[v]) over 64 feats --------------------

__launch_bounds__(256)
__global__ void decode_kernel(const float* __restrict__ Z, const int* __restrict__ eli,
                              float* __restrict__ out, int EL) {
    int tid = threadIdx.x;
    int e = blockIdx.x * 16 + (tid >> 4);
    int f4 = tid & 15;
    if (e >= EL) return;
    int u = eli[e];
    int v = eli[EL + e];
    const float4* Z4 = (const float4*)Z;
    float4 a = Z4[u * 16 + f4];
    float4 b = Z4[v * 16 + f4];
    float s = a.x * b.x + a.y * b.y + a.z * b.z + a.w * b.w;
    s += __shfl_xor(s, 1, 16);
    s += __shfl_xor(s, 2, 16);
    s += __shfl_xor(s, 4, 16);
    s += __shfl_xor(s, 8, 16);
    if (f4 == 0) out[e] = s;
}

// -------------------- launch --------------------

extern "C" void kernel_launch(void* const* d_in, const int* in_sizes, int n_in,
                              void* d_out, int out_size, void* d_ws, size_t ws_size,
                              hipStream_t stream) {
    const float* x   = (const float*)d_in[0];
    const int*   ei  = (const int*)d_in[1];
    const int*   eli = (const int*)d_in[2];
    const float* W1  = (const float*)d_in[3];
    const float* b1  = (const float*)d_in[4];
    const float* W2  = (const float*)d_in[5];
    const float* b2  = (const float*)d_in[6];
    float* out = (float*)d_out;

    int HID = in_sizes[4];            // 128
    int IN  = in_sizes[3] / HID;      // 128
    int N   = in_sizes[0] / IN;       // 50000
    int E   = in_sizes[1] / 2;        // 1600000
    int EL  = in_sizes[2] / 2;        // 200000

    // workspace carve-out (256B aligned)
    char* ws = (char*)d_ws;
    auto carve = [&](size_t bytes) -> void* {
        void* p = (void*)ws;
        ws += (bytes + 255) & ~(size_t)255;
        return p;
    };
    int*   cnt      = (int*)carve((size_t)N * 4);
    float* dinv     = (float*)carve((size_t)N * 4);
    int*   rp       = (int*)carve((size_t)N * 4);
    int*   pos      = (int*)carve((size_t)N * 4);
    int*   partials = (int*)carve(256 * 4);
    int*   col      = (int*)carve((size_t)E * 4);
    float* bufA     = (float*)carve((size_t)N * 128 * 4);
    float* bufB     = (float*)carve((size_t)N * 128 * 4);

    const int* src = ei;
    const int* dst = ei + E;

    int nb = (N + 255) / 256;

    hipMemsetAsync(cnt, 0, (size_t)N * 4, stream);
    hist_kernel<<<(E + 255) / 256, 256, 0, stream>>>(dst, cnt, E);
    dinv_kernel<<<nb, 256, 0, stream>>>(cnt, dinv, N);
    scan_a<<<nb, 256, 0, stream>>>(cnt, rp, partials, N);
    scan_b<<<1, 256, 0, stream>>>(partials, nb);
    scan_c<<<nb, 256, 0, stream>>>(rp, partials, pos, N);
    place_kernel<<<(E + 255) / 256, 256, 0, stream>>>(src, dst, pos, col, E);

    // layer 1: t = x@W1 ; h = relu(agg(t) + b1)
    gemm_k128<128><<<(N + 63) / 64, 256, 0, stream>>>(x, W1, bufA, N);
    agg_csr<128, true><<<(N + 7) / 8, 256, 0, stream>>>(bufA, dinv, rp, cnt, col, b1, bufB, N);

    // layer 2: t = h@W2 ; z = agg(t) + b2
    gemm_k128<64><<<(N + 63) / 64, 256, 0, stream>>>(bufB, W2, bufA, N);
    agg_csr<64, false><<<(N + 15) / 16, 256, 0, stream>>>(bufA, dinv, rp, cnt, col, b2, bufB, N);

    // decode
    decode_kernel<<<(EL + 15) / 16, 256, 0, stream>>>(bufB, eli, out, EL);
}

// Round 2
// 319.421 us; speedup vs baseline: 1.4560x; 1.4560x over previous
//
#include <hip/hip_runtime.h>
#include <hip/hip_bf16.h>

// ==================== binned CSR build ====================
// Bucket = dst >> 7  (128 nodes per bucket).  K = ceil(N/128) buckets.
// Edge record packed into one int: (dst&127)<<16 | src   (requires N <= 65536).

#define BKT_BITS 7
#define BKT_W    128

// Phase A: bucket histogram (LDS-local, then one global atomic per bucket per block)
__launch_bounds__(256)
__global__ void bucket_hist(const int* __restrict__ dst, int* __restrict__ bcnt,
                            int E, int K) {
    __shared__ int h[512];
    int t = threadIdx.x;
    for (int i = t; i < K; i += 256) h[i] = 0;
    __syncthreads();
    int base = blockIdx.x * 4096;
    int end = min(base + 4096, E);
    for (int i = base + t; i < end; i += 256)
        atomicAdd(&h[dst[i] >> BKT_BITS], 1);
    __syncthreads();
    for (int i = t; i < K; i += 256)
        if (h[i]) atomicAdd(&bcnt[i], h[i]);
}

// Phase B: exclusive scan of bucket counts (K <= 512, single block)
__launch_bounds__(512)
__global__ void bucket_scan(const int* __restrict__ bcnt, int* __restrict__ bbase,
                            int* __restrict__ bpos, int K) {
    __shared__ int sm[512];
    int t = threadIdx.x;
    int v = (t < K) ? bcnt[t] : 0;
    sm[t] = v;
    __syncthreads();
    for (int off = 1; off < 512; off <<= 1) {
        int u = (t >= off) ? sm[t - off] : 0;
        __syncthreads();
        sm[t] += u;
        __syncthreads();
    }
    if (t < K) {
        int e = sm[t] - v;
        bbase[t] = e;
        bpos[t] = e;
    }
}

// Phase C: scatter packed edges into bucket-ordered ebuf.
// Per-block per-bucket ranges reserved with one atomic -> sequential-ish writes.
__launch_bounds__(256)
__global__ void bucket_scatter(const int* __restrict__ src, const int* __restrict__ dst,
                               int* __restrict__ bpos, int* __restrict__ ebuf,
                               int E, int K) {
    __shared__ int h[512];
    __shared__ int start[512];
    int t = threadIdx.x;
    for (int i = t; i < K; i += 256) h[i] = 0;
    __syncthreads();
    int base = blockIdx.x * 8192;
    int end = min(base + 8192, E);
    for (int i = base + t; i < end; i += 256)
        atomicAdd(&h[dst[i] >> BKT_BITS], 1);
    __syncthreads();
    for (int i = t; i < K; i += 256) {
        int c = h[i];
        start[i] = c ? atomicAdd(&bpos[i], c) : 0;
        h[i] = 0;
    }
    __syncthreads();
    for (int i = base + t; i < end; i += 256) {
        int d = dst[i];
        int b = d >> BKT_BITS;
        int r = atomicAdd(&h[b], 1);
        ebuf[start[b] + r] = src[i] | ((d & (BKT_W - 1)) << 16);
    }
}

// Phase D: per-bucket CSR finalize — degrees, local scan, placement, dinv.
// One block per bucket; col write region is ~16 KB (stays hot in L2).
__launch_bounds__(256)
__global__ void bucket_csr(const int* __restrict__ ebuf, const int* __restrict__ bbase,
                           const int* __restrict__ bcnt, int* __restrict__ rp,
                           int* __restrict__ cnt, float* __restrict__ dinv,
                           int* __restrict__ col, int N) {
    __shared__ int deg[BKT_W];
    __shared__ int off[BKT_W];
    int b = blockIdx.x;
    int t = threadIdx.x;
    int base = bbase[b];
    int end = base + bcnt[b];
    if (t < BKT_W) deg[t] = 0;
    __syncthreads();
    for (int i = base + t; i < end; i += 256)
        atomicAdd(&deg[ebuf[i] >> 16], 1);
    __syncthreads();
    if (t < BKT_W) off[t] = deg[t];
    __syncthreads();
    for (int o = 1; o < BKT_W; o <<= 1) {
        int u = (t >= o && t < BKT_W) ? off[t - o] : 0;
        __syncthreads();
        if (t < BKT_W) off[t] += u;
        __syncthreads();
    }
    int node0 = b << BKT_BITS;
    if (t < BKT_W && node0 + t < N) {
        int ex = off[t] - deg[t];          // exclusive
        rp[node0 + t] = base + ex;
        cnt[node0 + t] = deg[t];
        dinv[node0 + t] = rsqrtf((float)deg[t] + 1.0f);
        off[t] = ex;                       // reuse as placement cursor
    }
    __syncthreads();
    for (int i = base + t; i < end; i += 256) {
        int p = ebuf[i];
        int r = atomicAdd(&off[p >> 16], 1);
        col[base + r] = p & 0xFFFF;
    }
}

// ==================== dense GEMM: Y[N,NC] = X[N,128] @ W[128,NC] ====================

template <int NC>
__launch_bounds__(256)
__global__ void gemm_k128(const float* __restrict__ X, const float* __restrict__ W,
                          float* __restrict__ Y, int N) {
    constexpr int CG = NC / 4;
    constexpr int RPT = CG / 4;
    constexpr int STRIDE = 132;
    __shared__ float xs[64 * STRIDE];

    int tid = threadIdx.x;
    int r0 = blockIdx.x * 64;
    const float4* X4 = (const float4*)X;

#pragma unroll
    for (int j = 0; j < 8; ++j) {
        int idx = tid + j * 256;
        int lr = idx >> 5;
        int lc = idx & 31;
        int gr = r0 + lr;
        float4 v = make_float4(0.f, 0.f, 0.f, 0.f);
        if (gr < N) v = X4[gr * 32 + lc];
        *(float4*)&xs[lr * STRIDE + lc * 4] = v;
    }
    __syncthreads();

    int cx = tid % CG;
    int ry = tid / CG;

    float4 acc[RPT];
#pragma unroll
    for (int i = 0; i < RPT; ++i) acc[i] = make_float4(0.f, 0.f, 0.f, 0.f);

    const float4* W4 = (const float4*)W;
#pragma unroll 4
    for (int k = 0; k < 128; ++k) {
        float4 wv = W4[k * CG + cx];
#pragma unroll
        for (int i = 0; i < RPT; ++i) {
            float xv = xs[(ry * RPT + i) * STRIDE + k];
            acc[i].x = fmaf(xv, wv.x, acc[i].x);
            acc[i].y = fmaf(xv, wv.y, acc[i].y);
            acc[i].z = fmaf(xv, wv.z, acc[i].z);
            acc[i].w = fmaf(xv, wv.w, acc[i].w);
        }
    }

    float4* Y4 = (float4*)Y;
#pragma unroll
    for (int i = 0; i < RPT; ++i) {
        int row = r0 + ry * RPT + i;
        if (row < N) Y4[row * CG + cx] = acc[i];
    }
}

// ==================== CSR aggregation ====================

template <int F, bool RELU>
__launch_bounds__(256)
__global__ void agg_csr(const float* __restrict__ T, const float* __restrict__ dinv,
                        const int* __restrict__ rp, const int* __restrict__ cnt,
                        const int* __restrict__ col, const float* __restrict__ bias,
                        float* __restrict__ O, int N) {
    constexpr int TPN = F / 4;
    constexpr int NPB = 256 / TPN;
    int tid = threadIdx.x;
    int node = blockIdx.x * NPB + tid / TPN;
    int f4 = tid % TPN;
    if (node >= N) return;

    const float4* T4 = (const float4*)T;
    float di = dinv[node];

    float4 s = T4[node * TPN + f4];
    s.x *= di; s.y *= di; s.z *= di; s.w *= di;

    int start = rp[node];
    int num = cnt[node];
    for (int k = 0; k < num; ++k) {
        int j = col[start + k];
        float dj = dinv[j];
        float4 v = T4[j * TPN + f4];
        s.x = fmaf(v.x, dj, s.x);
        s.y = fmaf(v.y, dj, s.y);
        s.z = fmaf(v.z, dj, s.z);
        s.w = fmaf(v.w, dj, s.w);
    }

    float4 b = ((const float4*)bias)[f4];
    float4 o;
    o.x = fmaf(s.x, di, b.x);
    o.y = fmaf(s.y, di, b.y);
    o.z = fmaf(s.z, di, b.z);
    o.w = fmaf(s.w, di, b.w);
    if (RELU) {
        o.x = fmaxf(o.x, 0.f);
        o.y = fmaxf(o.y, 0.f);
        o.z = fmaxf(o.z, 0.f);
        o.w = fmaxf(o.w, 0.f);
    }
    ((float4*)O)[node * TPN + f4] = o;
}

// ==================== decode ====================

__launch_bounds__(256)
__global__ void decode_kernel(const float* __restrict__ Z, const int* __restrict__ eli,
                              float* __restrict__ out, int EL) {
    int tid = threadIdx.x;
    int e = blockIdx.x * 16 + (tid >> 4);
    int f4 = tid & 15;
    if (e >= EL) return;
    int u = eli[e];
    int v = eli[EL + e];
    const float4* Z4 = (const float4*)Z;
    float4 a = Z4[u * 16 + f4];
    float4 b = Z4[v * 16 + f4];
    float s = a.x * b.x + a.y * b.y + a.z * b.z + a.w * b.w;
    s += __shfl_xor(s, 1, 16);
    s += __shfl_xor(s, 2, 16);
    s += __shfl_xor(s, 4, 16);
    s += __shfl_xor(s, 8, 16);
    if (f4 == 0) out[e] = s;
}

// ==================== launch ====================

extern "C" void kernel_launch(void* const* d_in, const int* in_sizes, int n_in,
                              void* d_out, int out_size, void* d_ws, size_t ws_size,
                              hipStream_t stream) {
    const float* x   = (const float*)d_in[0];
    const int*   ei  = (const int*)d_in[1];
    const int*   eli = (const int*)d_in[2];
    const float* W1  = (const float*)d_in[3];
    const float* b1  = (const float*)d_in[4];
    const float* W2  = (const float*)d_in[5];
    const float* b2  = (const float*)d_in[6];
    float* out = (float*)d_out;

    int HID = in_sizes[4];
    int IN  = in_sizes[3] / HID;
    int N   = in_sizes[0] / IN;
    int E   = in_sizes[1] / 2;
    int EL  = in_sizes[2] / 2;
    int K   = (N + BKT_W - 1) >> BKT_BITS;   // buckets

    char* ws = (char*)d_ws;
    auto carve = [&](size_t bytes) -> void* {
        void* p = (void*)ws;
        ws += (bytes + 255) & ~(size_t)255;
        return p;
    };
    int*   cnt   = (int*)carve((size_t)N * 4);
    float* dinv  = (float*)carve((size_t)N * 4);
    int*   rp    = (int*)carve((size_t)N * 4);
    int*   bcnt  = (int*)carve(512 * 4);
    int*   bbase = (int*)carve(512 * 4);
    int*   bpos  = (int*)carve(512 * 4);
    int*   col   = (int*)carve((size_t)E * 4);
    float* bufA  = (float*)carve((size_t)N * 128 * 4);
    float* bufB  = (float*)carve((size_t)N * 128 * 4);
    int*   ebuf  = (int*)bufA;   // alias: ebuf dead before gemm1 writes bufA

    const int* src = ei;
    const int* dst = ei + E;

    hipMemsetAsync(bcnt, 0, 512 * 4, stream);
    bucket_hist<<<(E + 4095) / 4096, 256, 0, stream>>>(dst, bcnt, E, K);
    bucket_scan<<<1, 512, 0, stream>>>(bcnt, bbase, bpos, K);
    bucket_scatter<<<(E + 8191) / 8192, 256, 0, stream>>>(src, dst, bpos, ebuf, E, K);
    bucket_csr<<<K, 256, 0, stream>>>(ebuf, bbase, bcnt, rp, cnt, dinv, col, N);

    // layer 1: t = x@W1 ; h = relu(agg(t) + b1)
    gemm_k128<128><<<(N + 63) / 64, 256, 0, stream>>>(x, W1, bufA, N);
    agg_csr<128, true><<<(N + 7) / 8, 256, 0, stream>>>(bufA, dinv, rp, cnt, col, b1, bufB, N);

    // layer 2: t = h@W2 ; z = agg(t) + b2
    gemm_k128<64><<<(N + 63) / 64, 256, 0, stream>>>(bufB, W2, bufA, N);
    agg_csr<64, false><<<(N + 15) / 16, 256, 0, stream>>>(bufA, dinv, rp, cnt, col, b2, bufB, N);

    // decode
    decode_kernel<<<(EL + 15) / 16, 256, 0, stream>>>(bufB, eli, out, EL);
}

// Round 3
// 218.878 us; speedup vs baseline: 2.1248x; 1.4594x over previous
//
#include <hip/hip_runtime.h>
#include <hip/hip_bf16.h>

typedef unsigned int uint;
typedef unsigned short ushort;

// -------- bf16 helpers (manual, RNE) --------
__device__ __forceinline__ ushort f2bf(float f) {
    uint u = __float_as_uint(f);
    uint r = 0x7FFFu + ((u >> 16) & 1u);
    return (ushort)((u + r) >> 16);
}
__device__ __forceinline__ void bf8_to_f(uint4 v, float* f) {
    f[0] = __uint_as_float(v.x << 16);
    f[1] = __uint_as_float(v.x & 0xFFFF0000u);
    f[2] = __uint_as_float(v.y << 16);
    f[3] = __uint_as_float(v.y & 0xFFFF0000u);
    f[4] = __uint_as_float(v.z << 16);
    f[5] = __uint_as_float(v.z & 0xFFFF0000u);
    f[6] = __uint_as_float(v.w << 16);
    f[7] = __uint_as_float(v.w & 0xFFFF0000u);
}

// ==================== binned CSR build ====================
// Bucket = dst >> 7 (128 nodes/bucket). Edge packed: (dst&127)<<16 | src  (N <= 65536).

#define BKT_BITS 7
#define BKT_W    128

__launch_bounds__(256)
__global__ void bucket_hist(const int* __restrict__ dst, int* __restrict__ bcnt,
                            int E, int K) {
    __shared__ int h[512];
    int t = threadIdx.x;
    for (int i = t; i < K; i += 256) h[i] = 0;
    __syncthreads();
    int base = blockIdx.x * 4096;
    int end = min(base + 4096, E);
    for (int i = base + t; i < end; i += 256)
        atomicAdd(&h[dst[i] >> BKT_BITS], 1);
    __syncthreads();
    for (int i = t; i < K; i += 256)
        if (h[i]) atomicAdd(&bcnt[i], h[i]);
}

__launch_bounds__(512)
__global__ void bucket_scan(const int* __restrict__ bcnt, int* __restrict__ bbase,
                            int* __restrict__ bpos, int K) {
    __shared__ int sm[512];
    int t = threadIdx.x;
    int v = (t < K) ? bcnt[t] : 0;
    sm[t] = v;
    __syncthreads();
    for (int off = 1; off < 512; off <<= 1) {
        int u = (t >= off) ? sm[t - off] : 0;
        __syncthreads();
        sm[t] += u;
        __syncthreads();
    }
    if (t < K) {
        int e = sm[t] - v;
        bbase[t] = e;
        bpos[t] = e;
    }
}

__launch_bounds__(256)
__global__ void bucket_scatter(const int* __restrict__ src, const int* __restrict__ dst,
                               int* __restrict__ bpos, int* __restrict__ ebuf,
                               int E, int K) {
    __shared__ int h[512];
    __shared__ int start[512];
    int t = threadIdx.x;
    for (int i = t; i < K; i += 256) h[i] = 0;
    __syncthreads();
    int base = blockIdx.x * 8192;
    int end = min(base + 8192, E);
    for (int i = base + t; i < end; i += 256)
        atomicAdd(&h[dst[i] >> BKT_BITS], 1);
    __syncthreads();
    for (int i = t; i < K; i += 256) {
        int c = h[i];
        start[i] = c ? atomicAdd(&bpos[i], c) : 0;
        h[i] = 0;
    }
    __syncthreads();
    for (int i = base + t; i < end; i += 256) {
        int d = dst[i];
        int b = d >> BKT_BITS;
        int r = atomicAdd(&h[b], 1);
        ebuf[start[b] + r] = src[i] | ((d & (BKT_W - 1)) << 16);
    }
}

__launch_bounds__(256)
__global__ void bucket_csr(const int* __restrict__ ebuf, const int* __restrict__ bbase,
                           const int* __restrict__ bcnt, int* __restrict__ rp,
                           int* __restrict__ cnt, float* __restrict__ dinv,
                           int* __restrict__ col, int N) {
    __shared__ int deg[BKT_W];
    __shared__ int off[BKT_W];
    int b = blockIdx.x;
    int t = threadIdx.x;
    int base = bbase[b];
    int end = base + bcnt[b];
    if (t < BKT_W) deg[t] = 0;
    __syncthreads();
    for (int i = base + t; i < end; i += 256)
        atomicAdd(&deg[ebuf[i] >> 16], 1);
    __syncthreads();
    if (t < BKT_W) off[t] = deg[t];
    __syncthreads();
    for (int o = 1; o < BKT_W; o <<= 1) {
        int u = (t >= o && t < BKT_W) ? off[t - o] : 0;
        __syncthreads();
        if (t < BKT_W) off[t] += u;
        __syncthreads();
    }
    int node0 = b << BKT_BITS;
    if (t < BKT_W && node0 + t < N) {
        int ex = off[t] - deg[t];
        rp[node0 + t] = base + ex;
        cnt[node0 + t] = deg[t];
        dinv[node0 + t] = rsqrtf((float)deg[t] + 1.0f);
        off[t] = ex;
    }
    __syncthreads();
    for (int i = base + t; i < end; i += 256) {
        int p = ebuf[i];
        int r = atomicAdd(&off[p >> 16], 1);
        col[base + r] = p & 0xFFFF;
    }
}

// ==================== dense GEMM: Yb[N,NC](bf16) = X[N,128] @ W[128,NC] ====================

template <int NC>
__launch_bounds__(256)
__global__ void gemm_k128_bf16out(const float* __restrict__ X, const float* __restrict__ W,
                                  ushort* __restrict__ Y, int N) {
    constexpr int CG = NC / 4;
    constexpr int RPT = CG / 4;
    constexpr int STRIDE = 132;
    __shared__ float xs[64 * STRIDE];

    int tid = threadIdx.x;
    int r0 = blockIdx.x * 64;
    const float4* X4 = (const float4*)X;

#pragma unroll
    for (int j = 0; j < 8; ++j) {
        int idx = tid + j * 256;
        int lr = idx >> 5;
        int lc = idx & 31;
        int gr = r0 + lr;
        float4 v = make_float4(0.f, 0.f, 0.f, 0.f);
        if (gr < N) v = X4[gr * 32 + lc];
        *(float4*)&xs[lr * STRIDE + lc * 4] = v;
    }
    __syncthreads();

    int cx = tid % CG;
    int ry = tid / CG;

    float4 acc[RPT];
#pragma unroll
    for (int i = 0; i < RPT; ++i) acc[i] = make_float4(0.f, 0.f, 0.f, 0.f);

    const float4* W4 = (const float4*)W;
#pragma unroll 4
    for (int k = 0; k < 128; ++k) {
        float4 wv = W4[k * CG + cx];
#pragma unroll
        for (int i = 0; i < RPT; ++i) {
            float xv = xs[(ry * RPT + i) * STRIDE + k];
            acc[i].x = fmaf(xv, wv.x, acc[i].x);
            acc[i].y = fmaf(xv, wv.y, acc[i].y);
            acc[i].z = fmaf(xv, wv.z, acc[i].z);
            acc[i].w = fmaf(xv, wv.w, acc[i].w);
        }
    }

    ushort4* Y4 = (ushort4*)Y;
#pragma unroll
    for (int i = 0; i < RPT; ++i) {
        int row = r0 + ry * RPT + i;
        if (row < N) {
            ushort4 o;
            o.x = f2bf(acc[i].x);
            o.y = f2bf(acc[i].y);
            o.z = f2bf(acc[i].z);
            o.w = f2bf(acc[i].w);
            Y4[row * CG + cx] = o;
        }
    }
}

// ==================== CSR aggregation, bf16 gather ====================
// F=128: 16 lanes/node, each lane owns 8 features (one uint4 = 8 bf16).

__launch_bounds__(256)
__global__ void agg_bf16_f128(const ushort* __restrict__ Tb, const float* __restrict__ dinv,
                              const int* __restrict__ rp, const int* __restrict__ cnt,
                              const int* __restrict__ col, const float* __restrict__ bias,
                              float* __restrict__ O, int N) {
    int tid = threadIdx.x;
    int node = blockIdx.x * 16 + (tid >> 4);
    int f4 = tid & 15;
    if (node >= N) return;

    const uint4* T4 = (const uint4*)Tb;
    float di = dinv[node];

    float acc[8], tmp[8];
    bf8_to_f(T4[node * 16 + f4], tmp);
#pragma unroll
    for (int i = 0; i < 8; ++i) acc[i] = tmp[i] * di;

    int start = rp[node];
    int num = cnt[node];
    int k = 0;
    for (; k + 4 <= num; k += 4) {
        int j0 = col[start + k];
        int j1 = col[start + k + 1];
        int j2 = col[start + k + 2];
        int j3 = col[start + k + 3];
        float d0 = dinv[j0], d1 = dinv[j1], d2 = dinv[j2], d3 = dinv[j3];
        uint4 v0 = T4[j0 * 16 + f4];
        uint4 v1 = T4[j1 * 16 + f4];
        uint4 v2 = T4[j2 * 16 + f4];
        uint4 v3 = T4[j3 * 16 + f4];
        float t0[8], t1[8], t2[8], t3[8];
        bf8_to_f(v0, t0); bf8_to_f(v1, t1); bf8_to_f(v2, t2); bf8_to_f(v3, t3);
#pragma unroll
        for (int i = 0; i < 8; ++i) {
            acc[i] = fmaf(t0[i], d0, acc[i]);
            acc[i] = fmaf(t1[i], d1, acc[i]);
            acc[i] = fmaf(t2[i], d2, acc[i]);
            acc[i] = fmaf(t3[i], d3, acc[i]);
        }
    }
    for (; k < num; ++k) {
        int j = col[start + k];
        float dj = dinv[j];
        bf8_to_f(T4[j * 16 + f4], tmp);
#pragma unroll
        for (int i = 0; i < 8; ++i) acc[i] = fmaf(tmp[i], dj, acc[i]);
    }

    float4 b0 = *(const float4*)&bias[f4 * 8];
    float4 b1 = *(const float4*)&bias[f4 * 8 + 4];
    float4 o0, o1;
    o0.x = fmaxf(fmaf(acc[0], di, b0.x), 0.f);
    o0.y = fmaxf(fmaf(acc[1], di, b0.y), 0.f);
    o0.z = fmaxf(fmaf(acc[2], di, b0.z), 0.f);
    o0.w = fmaxf(fmaf(acc[3], di, b0.w), 0.f);
    o1.x = fmaxf(fmaf(acc[4], di, b1.x), 0.f);
    o1.y = fmaxf(fmaf(acc[5], di, b1.y), 0.f);
    o1.z = fmaxf(fmaf(acc[6], di, b1.z), 0.f);
    o1.w = fmaxf(fmaf(acc[7], di, b1.w), 0.f);
    float4* Op = (float4*)&O[node * 128 + f4 * 8];
    Op[0] = o0;
    Op[1] = o1;
}

// F=64: 8 lanes/node, each lane owns 8 features. No ReLU (layer 2).

__launch_bounds__(256)
__global__ void agg_bf16_f64(const ushort* __restrict__ Tb, const float* __restrict__ dinv,
                             const int* __restrict__ rp, const int* __restrict__ cnt,
                             const int* __restrict__ col, const float* __restrict__ bias,
                             float* __restrict__ O, int N) {
    int tid = threadIdx.x;
    int node = blockIdx.x * 32 + (tid >> 3);
    int f4 = tid & 7;
    if (node >= N) return;

    const uint4* T4 = (const uint4*)Tb;
    float di = dinv[node];

    float acc[8], tmp[8];
    bf8_to_f(T4[node * 8 + f4], tmp);
#pragma unroll
    for (int i = 0; i < 8; ++i) acc[i] = tmp[i] * di;

    int start = rp[node];
    int num = cnt[node];
    int k = 0;
    for (; k + 4 <= num; k += 4) {
        int j0 = col[start + k];
        int j1 = col[start + k + 1];
        int j2 = col[start + k + 2];
        int j3 = col[start + k + 3];
        float d0 = dinv[j0], d1 = dinv[j1], d2 = dinv[j2], d3 = dinv[j3];
        uint4 v0 = T4[j0 * 8 + f4];
        uint4 v1 = T4[j1 * 8 + f4];
        uint4 v2 = T4[j2 * 8 + f4];
        uint4 v3 = T4[j3 * 8 + f4];
        float t0[8], t1[8], t2[8], t3[8];
        bf8_to_f(v0, t0); bf8_to_f(v1, t1); bf8_to_f(v2, t2); bf8_to_f(v3, t3);
#pragma unroll
        for (int i = 0; i < 8; ++i) {
            acc[i] = fmaf(t0[i], d0, acc[i]);
            acc[i] = fmaf(t1[i], d1, acc[i]);
            acc[i] = fmaf(t2[i], d2, acc[i]);
            acc[i] = fmaf(t3[i], d3, acc[i]);
        }
    }
    for (; k < num; ++k) {
        int j = col[start + k];
        float dj = dinv[j];
        bf8_to_f(T4[j * 8 + f4], tmp);
#pragma unroll
        for (int i = 0; i < 8; ++i) acc[i] = fmaf(tmp[i], dj, acc[i]);
    }

    float4 b0 = *(const float4*)&bias[f4 * 8];
    float4 b1 = *(const float4*)&bias[f4 * 8 + 4];
    float4 o0, o1;
    o0.x = fmaf(acc[0], di, b0.x);
    o0.y = fmaf(acc[1], di, b0.y);
    o0.z = fmaf(acc[2], di, b0.z);
    o0.w = fmaf(acc[3], di, b0.w);
    o1.x = fmaf(acc[4], di, b1.x);
    o1.y = fmaf(acc[5], di, b1.y);
    o1.z = fmaf(acc[6], di, b1.z);
    o1.w = fmaf(acc[7], di, b1.w);
    float4* Op = (float4*)&O[node * 64 + f4 * 8];
    Op[0] = o0;
    Op[1] = o1;
}

// ==================== decode ====================

__launch_bounds__(256)
__global__ void decode_kernel(const float* __restrict__ Z, const int* __restrict__ eli,
                              float* __restrict__ out, int EL) {
    int tid = threadIdx.x;
    int e = blockIdx.x * 16 + (tid >> 4);
    int f4 = tid & 15;
    if (e >= EL) return;
    int u = eli[e];
    int v = eli[EL + e];
    const float4* Z4 = (const float4*)Z;
    float4 a = Z4[u * 16 + f4];
    float4 b = Z4[v * 16 + f4];
    float s = a.x * b.x + a.y * b.y + a.z * b.z + a.w * b.w;
    s += __shfl_xor(s, 1, 16);
    s += __shfl_xor(s, 2, 16);
    s += __shfl_xor(s, 4, 16);
    s += __shfl_xor(s, 8, 16);
    if (f4 == 0) out[e] = s;
}

// ==================== launch ====================

extern "C" void kernel_launch(void* const* d_in, const int* in_sizes, int n_in,
                              void* d_out, int out_size, void* d_ws, size_t ws_size,
                              hipStream_t stream) {
    const float* x   = (const float*)d_in[0];
    const int*   ei  = (const int*)d_in[1];
    const int*   eli = (const int*)d_in[2];
    const float* W1  = (const float*)d_in[3];
    const float* b1  = (const float*)d_in[4];
    const float* W2  = (const float*)d_in[5];
    const float* b2  = (const float*)d_in[6];
    float* out = (float*)d_out;

    int HID = in_sizes[4];
    int IN  = in_sizes[3] / HID;
    int N   = in_sizes[0] / IN;
    int E   = in_sizes[1] / 2;
    int EL  = in_sizes[2] / 2;
    int K   = (N + BKT_W - 1) >> BKT_BITS;

    char* ws = (char*)d_ws;
    auto carve = [&](size_t bytes) -> void* {
        void* p = (void*)ws;
        ws += (bytes + 255) & ~(size_t)255;
        return p;
    };
    int*    cnt   = (int*)carve((size_t)N * 4);
    float*  dinv  = (float*)carve((size_t)N * 4);
    int*    rp    = (int*)carve((size_t)N * 4);
    int*    bcnt  = (int*)carve(512 * 4);
    int*    bbase = (int*)carve(512 * 4);
    int*    bpos  = (int*)carve(512 * 4);
    int*    col   = (int*)carve((size_t)E * 4);
    ushort* tbuf  = (ushort*)carve((size_t)N * 128 * 2);  // bf16 t1 / t2
    float*  hbuf  = (float*)carve((size_t)N * 128 * 4);   // fp32 h
    float*  zbuf  = (float*)carve((size_t)N * 64 * 4);    // fp32 z
    int*    ebuf  = (int*)tbuf;   // alias: ebuf dead before gemm1 writes tbuf

    const int* src = ei;
    const int* dst = ei + E;

    hipMemsetAsync(bcnt, 0, 512 * 4, stream);
    bucket_hist<<<(E + 4095) / 4096, 256, 0, stream>>>(dst, bcnt, E, K);
    bucket_scan<<<1, 512, 0, stream>>>(bcnt, bbase, bpos, K);
    bucket_scatter<<<(E + 8191) / 8192, 256, 0, stream>>>(src, dst, bpos, ebuf, E, K);
    bucket_csr<<<K, 256, 0, stream>>>(ebuf, bbase, bcnt, rp, cnt, dinv, col, N);

    // layer 1: t1 = x@W1 (bf16) ; h = relu(agg(t1) + b1)  (fp32)
    gemm_k128_bf16out<128><<<(N + 63) / 64, 256, 0, stream>>>(x, W1, tbuf, N);
    agg_bf16_f128<<<(N + 15) / 16, 256, 0, stream>>>(tbuf, dinv, rp, cnt, col, b1, hbuf, N);

    // layer 2: t2 = h@W2 (bf16) ; z = agg(t2) + b2  (fp32)
    gemm_k128_bf16out<64><<<(N + 63) / 64, 256, 0, stream>>>(hbuf, W2, tbuf, N);
    agg_bf16_f64<<<(N + 31) / 32, 256, 0, stream>>>(tbuf, dinv, rp, cnt, col, b2, zbuf, N);

    // decode
    decode_kernel<<<(EL + 15) / 16, 256, 0, stream>>>(zbuf, eli, out, EL);
}

// Round 4
// 181.147 us; speedup vs baseline: 2.5674x; 1.2083x over previous
//
#include <hip/hip_runtime.h>
#include <hip/hip_bf16.h>

typedef unsigned int uint;
typedef unsigned short ushort;
typedef short bf16x8_t __attribute__((ext_vector_type(8)));
typedef float f32x4_t __attribute__((ext_vector_type(4)));

// -------- bf16 helpers (manual, RNE) --------
__device__ __forceinline__ ushort f2bf(float f) {
    uint u = __float_as_uint(f);
    uint r = 0x7FFFu + ((u >> 16) & 1u);
    return (ushort)((u + r) >> 16);
}
__device__ __forceinline__ void bf8_to_f(uint4 v, float* f) {
    f[0] = __uint_as_float(v.x << 16);
    f[1] = __uint_as_float(v.x & 0xFFFF0000u);
    f[2] = __uint_as_float(v.y << 16);
    f[3] = __uint_as_float(v.y & 0xFFFF0000u);
    f[4] = __uint_as_float(v.z << 16);
    f[5] = __uint_as_float(v.z & 0xFFFF0000u);
    f[6] = __uint_as_float(v.w << 16);
    f[7] = __uint_as_float(v.w & 0xFFFF0000u);
}

// ==================== binned CSR build ====================
#define BKT_BITS 7
#define BKT_W    128

__launch_bounds__(256)
__global__ void bucket_hist(const int* __restrict__ dst, int* __restrict__ bcnt,
                            int E, int K) {
    __shared__ int h[512];
    int t = threadIdx.x;
    for (int i = t; i < K; i += 256) h[i] = 0;
    __syncthreads();
    int base = blockIdx.x * 4096;
    int end = min(base + 4096, E);
    for (int i = base + t; i < end; i += 256)
        atomicAdd(&h[dst[i] >> BKT_BITS], 1);
    __syncthreads();
    for (int i = t; i < K; i += 256)
        if (h[i]) atomicAdd(&bcnt[i], h[i]);
}

__launch_bounds__(512)
__global__ void bucket_scan(const int* __restrict__ bcnt, int* __restrict__ bbase,
                            int* __restrict__ bpos, int K) {
    __shared__ int sm[512];
    int t = threadIdx.x;
    int v = (t < K) ? bcnt[t] : 0;
    sm[t] = v;
    __syncthreads();
    for (int off = 1; off < 512; off <<= 1) {
        int u = (t >= off) ? sm[t - off] : 0;
        __syncthreads();
        sm[t] += u;
        __syncthreads();
    }
    if (t < K) {
        int e = sm[t] - v;
        bbase[t] = e;
        bpos[t] = e;
    }
}

__launch_bounds__(256)
__global__ void bucket_scatter(const int* __restrict__ src, const int* __restrict__ dst,
                               int* __restrict__ bpos, int* __restrict__ ebuf,
                               int E, int K) {
    __shared__ int h[512];
    __shared__ int start[512];
    int t = threadIdx.x;
    for (int i = t; i < K; i += 256) h[i] = 0;
    __syncthreads();
    int base = blockIdx.x * 8192;
    int end = min(base + 8192, E);
    for (int i = base + t; i < end; i += 256)
        atomicAdd(&h[dst[i] >> BKT_BITS], 1);
    __syncthreads();
    for (int i = t; i < K; i += 256) {
        int c = h[i];
        start[i] = c ? atomicAdd(&bpos[i], c) : 0;
        h[i] = 0;
    }
    __syncthreads();
    for (int i = base + t; i < end; i += 256) {
        int d = dst[i];
        int b = d >> BKT_BITS;
        int r = atomicAdd(&h[b], 1);
        ebuf[start[b] + r] = src[i] | ((d & (BKT_W - 1)) << 16);
    }
}

__launch_bounds__(256)
__global__ void bucket_csr(const int* __restrict__ ebuf, const int* __restrict__ bbase,
                           const int* __restrict__ bcnt, int* __restrict__ rp,
                           int* __restrict__ cnt, float* __restrict__ dinv,
                           int* __restrict__ col, int N) {
    __shared__ int deg[BKT_W];
    __shared__ int off[BKT_W];
    int b = blockIdx.x;
    int t = threadIdx.x;
    int base = bbase[b];
    int end = base + bcnt[b];
    if (t < BKT_W) deg[t] = 0;
    __syncthreads();
    for (int i = base + t; i < end; i += 256)
        atomicAdd(&deg[ebuf[i] >> 16], 1);
    __syncthreads();
    if (t < BKT_W) off[t] = deg[t];
    __syncthreads();
    for (int o = 1; o < BKT_W; o <<= 1) {
        int u = (t >= o && t < BKT_W) ? off[t - o] : 0;
        __syncthreads();
        if (t < BKT_W) off[t] += u;
        __syncthreads();
    }
    int node0 = b << BKT_BITS;
    if (t < BKT_W && node0 + t < N) {
        int ex = off[t] - deg[t];
        rp[node0 + t] = base + ex;
        cnt[node0 + t] = deg[t];
        dinv[node0 + t] = rsqrtf((float)deg[t] + 1.0f);
        off[t] = ex;
    }
    __syncthreads();
    for (int i = base + t; i < end; i += 256) {
        int p = ebuf[i];
        int r = atomicAdd(&off[p >> 16], 1);
        col[base + r] = p & 0xFFFF;
    }
}

// ==================== W^T bf16 prep ====================
// wt1[n*128+k] = bf(W1[k*128+n])  (128x128);  wt2[n*128+k] = bf(W2[k*64+n])  (128x64 -> 64x128)
__launch_bounds__(256)
__global__ void prep_wt(const float* __restrict__ W1, const float* __restrict__ W2,
                        ushort* __restrict__ wt1, ushort* __restrict__ wt2) {
    int t = blockIdx.x * 256 + threadIdx.x;
    if (t < 128 * 128) {
        int n = t >> 7, k = t & 127;
        wt1[n * 128 + k] = f2bf(W1[k * 128 + n]);
    }
    if (t < 64 * 128) {
        int n = t >> 7, k = t & 127;
        wt2[n * 128 + k] = f2bf(W2[k * 64 + n]);
    }
}

// ==================== MFMA GEMM: Y[N,NC](bf16) = X[N,128] @ W[128,NC] ====================
// Wt = W^T bf16 [NC][128]. XBF16: X already bf16 [N][128]; else fp32.
// Block: 256 thr (4 waves), 64 rows. Wave w owns rows w*16..w*16+15, all NC cols.
// LDS XOR-swizzle: byte ^= (row&7)<<4  (conflict-free ds_read_b128 fragments).

template <int NC, bool XBF16>
__launch_bounds__(256)
__global__ void gemm_mfma(const void* __restrict__ Xv, const ushort* __restrict__ Wt,
                          ushort* __restrict__ Y, int N) {
    __shared__ ushort As[64 * 128];       // 16 KB
    __shared__ ushort Bs[NC * 128];       // 32/16 KB ; reused as repack buffer

    int tid = threadIdx.x;
    int r0 = blockIdx.x * 64;

    // ---- stage A (64 x 128 bf16, swizzled) ----
    if (XBF16) {
        const uint4* X4 = (const uint4*)Xv;     // 16 uint4 per row
#pragma unroll
        for (int j = 0; j < 4; ++j) {
            int idx = tid + j * 256;            // 1024 slots
            int lr = idx >> 4;
            int lc = idx & 15;
            int gr = r0 + lr;
            uint4 v = (gr < N) ? X4[(size_t)gr * 16 + lc] : make_uint4(0, 0, 0, 0);
            int boff = (lr * 256 + lc * 16) ^ ((lr & 7) << 4);
            *(uint4*)((char*)As + boff) = v;
        }
    } else {
        const float4* X4 = (const float4*)Xv;   // 32 float4 per row
#pragma unroll
        for (int j = 0; j < 8; ++j) {
            int idx = tid + j * 256;            // 2048 slots
            int lr = idx >> 5;
            int lc = idx & 31;
            int gr = r0 + lr;
            float4 v = (gr < N) ? X4[(size_t)gr * 32 + lc] : make_float4(0.f, 0.f, 0.f, 0.f);
            ushort4 o;
            o.x = f2bf(v.x); o.y = f2bf(v.y); o.z = f2bf(v.z); o.w = f2bf(v.w);
            int boff = (lr * 256 + lc * 8) ^ ((lr & 7) << 4);
            *(ushort4*)((char*)As + boff) = o;
        }
    }

    // ---- stage B = W^T (NC x 128 bf16, swizzled) ----
    {
        const uint4* Wt4 = (const uint4*)Wt;
        constexpr int BSLOTS = NC * 16;         // uint4 count
#pragma unroll
        for (int j = 0; j < BSLOTS / 256; ++j) {
            int idx = tid + j * 256;
            int n = idx >> 4;
            int c = idx & 15;
            uint4 v = Wt4[idx];
            int boff = (n * 256 + c * 16) ^ ((n & 7) << 4);
            *(uint4*)((char*)Bs + boff) = v;
        }
    }
    __syncthreads();

    // ---- MFMA compute ----
    int wave = tid >> 6;
    int lane = tid & 63;
    int l15 = lane & 15;
    int kgrp = lane >> 4;                       // 0..3
    int arow = wave * 16 + l15;

    f32x4_t acc[NC / 16];
#pragma unroll
    for (int n = 0; n < NC / 16; ++n) acc[n] = (f32x4_t){0.f, 0.f, 0.f, 0.f};

#pragma unroll
    for (int ks = 0; ks < 4; ++ks) {
        int aoff = (arow * 256 + ks * 64 + kgrp * 16) ^ ((arow & 7) << 4);
        bf16x8_t a = *(const bf16x8_t*)((const char*)As + aoff);
#pragma unroll
        for (int n = 0; n < NC / 16; ++n) {
            int bcol = n * 16 + l15;
            int boff = (bcol * 256 + ks * 64 + kgrp * 16) ^ ((bcol & 7) << 4);
            bf16x8_t b = *(const bf16x8_t*)((const char*)Bs + boff);
            acc[n] = __builtin_amdgcn_mfma_f32_16x16x32_bf16(a, b, acc[n], 0, 0, 0);
        }
    }

    // ---- repack through LDS (padded stride) + coalesced store ----
    __syncthreads();                            // Bs reads done; reuse as repack buf
    ushort* Rs = (ushort*)Bs;
    constexpr int RST = NC + 8;                 // padded ushort stride (16B-aligned rows)
#pragma unroll
    for (int n = 0; n < NC / 16; ++n)
#pragma unroll
        for (int r = 0; r < 4; ++r) {
            int row = wave * 16 + kgrp * 4 + r; // C/D: col=lane&15, row=(lane>>4)*4+reg
            int colc = n * 16 + l15;
            Rs[row * RST + colc] = f2bf(acc[n][r]);
        }
    __syncthreads();

    constexpr int CPR = NC / 8;                 // uint4 per output row
    constexpr int OS = 64 * CPR;
#pragma unroll
    for (int j = 0; j < OS / 256; ++j) {
        int idx = tid + j * 256;
        int row = idx / CPR;
        int c = idx % CPR;
        int gr = r0 + row;
        if (gr < N)
            ((uint4*)Y)[(size_t)gr * CPR + c] = *(const uint4*)&Rs[row * RST + c * 8];
    }
}

// ==================== CSR aggregation, bf16 gather, bf16 out ====================
// F=128: 16 lanes/node, lane owns 8 feats (uint4).

__launch_bounds__(256)
__global__ void agg_bf16_f128(const ushort* __restrict__ Tb, const float* __restrict__ dinv,
                              const int* __restrict__ rp, const int* __restrict__ cnt,
                              const int* __restrict__ col, const float* __restrict__ bias,
                              ushort* __restrict__ O, int N) {
    int tid = threadIdx.x;
    int node = blockIdx.x * 16 + (tid >> 4);
    int f4 = tid & 15;
    if (node >= N) return;

    const uint4* T4 = (const uint4*)Tb;
    float di = dinv[node];

    float acc[8], tmp[8];
    bf8_to_f(T4[node * 16 + f4], tmp);
#pragma unroll
    for (int i = 0; i < 8; ++i) acc[i] = tmp[i] * di;

    int start = rp[node];
    int num = cnt[node];
    int k = 0;
    for (; k + 4 <= num; k += 4) {
        int j0 = col[start + k];
        int j1 = col[start + k + 1];
        int j2 = col[start + k + 2];
        int j3 = col[start + k + 3];
        float d0 = dinv[j0], d1 = dinv[j1], d2 = dinv[j2], d3 = dinv[j3];
        uint4 v0 = T4[j0 * 16 + f4];
        uint4 v1 = T4[j1 * 16 + f4];
        uint4 v2 = T4[j2 * 16 + f4];
        uint4 v3 = T4[j3 * 16 + f4];
        float t0[8], t1[8], t2[8], t3[8];
        bf8_to_f(v0, t0); bf8_to_f(v1, t1); bf8_to_f(v2, t2); bf8_to_f(v3, t3);
#pragma unroll
        for (int i = 0; i < 8; ++i) {
            acc[i] = fmaf(t0[i], d0, acc[i]);
            acc[i] = fmaf(t1[i], d1, acc[i]);
            acc[i] = fmaf(t2[i], d2, acc[i]);
            acc[i] = fmaf(t3[i], d3, acc[i]);
        }
    }
    for (; k < num; ++k) {
        int j = col[start + k];
        float dj = dinv[j];
        bf8_to_f(T4[j * 16 + f4], tmp);
#pragma unroll
        for (int i = 0; i < 8; ++i) acc[i] = fmaf(tmp[i], dj, acc[i]);
    }

    uint out[4];
#pragma unroll
    for (int i = 0; i < 4; ++i) {
        float lo = fmaxf(fmaf(acc[2 * i], di, bias[f4 * 8 + 2 * i]), 0.f);
        float hi = fmaxf(fmaf(acc[2 * i + 1], di, bias[f4 * 8 + 2 * i + 1]), 0.f);
        out[i] = (uint)f2bf(lo) | ((uint)f2bf(hi) << 16);
    }
    *(uint4*)&O[node * 128 + f4 * 8] = make_uint4(out[0], out[1], out[2], out[3]);
}

// F=64: 8 lanes/node. No ReLU.

__launch_bounds__(256)
__global__ void agg_bf16_f64(const ushort* __restrict__ Tb, const float* __restrict__ dinv,
                             const int* __restrict__ rp, const int* __restrict__ cnt,
                             const int* __restrict__ col, const float* __restrict__ bias,
                             ushort* __restrict__ O, int N) {
    int tid = threadIdx.x;
    int node = blockIdx.x * 32 + (tid >> 3);
    int f4 = tid & 7;
    if (node >= N) return;

    const uint4* T4 = (const uint4*)Tb;
    float di = dinv[node];

    float acc[8], tmp[8];
    bf8_to_f(T4[node * 8 + f4], tmp);
#pragma unroll
    for (int i = 0; i < 8; ++i) acc[i] = tmp[i] * di;

    int start = rp[node];
    int num = cnt[node];
    int k = 0;
    for (; k + 4 <= num; k += 4) {
        int j0 = col[start + k];
        int j1 = col[start + k + 1];
        int j2 = col[start + k + 2];
        int j3 = col[start + k + 3];
        float d0 = dinv[j0], d1 = dinv[j1], d2 = dinv[j2], d3 = dinv[j3];
        uint4 v0 = T4[j0 * 8 + f4];
        uint4 v1 = T4[j1 * 8 + f4];
        uint4 v2 = T4[j2 * 8 + f4];
        uint4 v3 = T4[j3 * 8 + f4];
        float t0[8], t1[8], t2[8], t3[8];
        bf8_to_f(v0, t0); bf8_to_f(v1, t1); bf8_to_f(v2, t2); bf8_to_f(v3, t3);
#pragma unroll
        for (int i = 0; i < 8; ++i) {
            acc[i] = fmaf(t0[i], d0, acc[i]);
            acc[i] = fmaf(t1[i], d1, acc[i]);
            acc[i] = fmaf(t2[i], d2, acc[i]);
            acc[i] = fmaf(t3[i], d3, acc[i]);
        }
    }
    for (; k < num; ++k) {
        int j = col[start + k];
        float dj = dinv[j];
        bf8_to_f(T4[j * 8 + f4], tmp);
#pragma unroll
        for (int i = 0; i < 8; ++i) acc[i] = fmaf(tmp[i], dj, acc[i]);
    }

    uint out[4];
#pragma unroll
    for (int i = 0; i < 4; ++i) {
        float lo = fmaf(acc[2 * i], di, bias[f4 * 8 + 2 * i]);
        float hi = fmaf(acc[2 * i + 1], di, bias[f4 * 8 + 2 * i + 1]);
        out[i] = (uint)f2bf(lo) | ((uint)f2bf(hi) << 16);
    }
    *(uint4*)&O[node * 64 + f4 * 8] = make_uint4(out[0], out[1], out[2], out[3]);
}

// ==================== decode: logits[e] = dot(z[u], z[v]), z bf16 [N][64] ====================

__launch_bounds__(256)
__global__ void decode_kernel(const ushort* __restrict__ Zb, const int* __restrict__ eli,
                              float* __restrict__ out, int EL) {
    int tid = threadIdx.x;
    int e = blockIdx.x * 32 + (tid >> 3);
    int f = tid & 7;
    if (e >= EL) return;
    int u = eli[e];
    int v = eli[EL + e];
    const uint4* Z4 = (const uint4*)Zb;
    float a[8], b[8];
    bf8_to_f(Z4[u * 8 + f], a);
    bf8_to_f(Z4[v * 8 + f], b);
    float s = 0.f;
#pragma unroll
    for (int i = 0; i < 8; ++i) s = fmaf(a[i], b[i], s);
    s += __shfl_xor(s, 1, 8);
    s += __shfl_xor(s, 2, 8);
    s += __shfl_xor(s, 4, 8);
    if (f == 0) out[e] = s;
}

// ==================== launch ====================

extern "C" void kernel_launch(void* const* d_in, const int* in_sizes, int n_in,
                              void* d_out, int out_size, void* d_ws, size_t ws_size,
                              hipStream_t stream) {
    const float* x   = (const float*)d_in[0];
    const int*   ei  = (const int*)d_in[1];
    const int*   eli = (const int*)d_in[2];
    const float* W1  = (const float*)d_in[3];
    const float* b1  = (const float*)d_in[4];
    const float* W2  = (const float*)d_in[5];
    const float* b2  = (const float*)d_in[6];
    float* out = (float*)d_out;

    int HID = in_sizes[4];
    int IN  = in_sizes[3] / HID;
    int N   = in_sizes[0] / IN;
    int E   = in_sizes[1] / 2;
    int EL  = in_sizes[2] / 2;
    int K   = (N + BKT_W - 1) >> BKT_BITS;

    char* ws = (char*)d_ws;
    auto carve = [&](size_t bytes) -> void* {
        void* p = (void*)ws;
        ws += (bytes + 255) & ~(size_t)255;
        return p;
    };
    int*    cnt   = (int*)carve((size_t)N * 4);
    float*  dinv  = (float*)carve((size_t)N * 4);
    int*    rp    = (int*)carve((size_t)N * 4);
    int*    bcnt  = (int*)carve(512 * 4);
    int*    bbase = (int*)carve(512 * 4);
    int*    bpos  = (int*)carve(512 * 4);
    int*    col   = (int*)carve((size_t)E * 4);
    ushort* wt1   = (ushort*)carve(128 * 128 * 2);
    ushort* wt2   = (ushort*)carve(64 * 128 * 2);
    ushort* tbuf  = (ushort*)carve((size_t)N * 128 * 2);  // bf16 t1 / t2
    ushort* hbuf  = (ushort*)carve((size_t)N * 128 * 2);  // bf16 h
    ushort* zbuf  = (ushort*)carve((size_t)N * 64 * 2);   // bf16 z
    int*    ebuf  = (int*)tbuf;   // alias: ebuf dead before gemm1 writes tbuf

    const int* src = ei;
    const int* dst = ei + E;

    prep_wt<<<64, 256, 0, stream>>>(W1, W2, wt1, wt2);
    hipMemsetAsync(bcnt, 0, 512 * 4, stream);
    bucket_hist<<<(E + 4095) / 4096, 256, 0, stream>>>(dst, bcnt, E, K);
    bucket_scan<<<1, 512, 0, stream>>>(bcnt, bbase, bpos, K);
    bucket_scatter<<<(E + 8191) / 8192, 256, 0, stream>>>(src, dst, bpos, ebuf, E, K);
    bucket_csr<<<K, 256, 0, stream>>>(ebuf, bbase, bcnt, rp, cnt, dinv, col, N);

    // layer 1: t1 = bf16(x) @ bf16(W1)  (MFMA) ; h = bf16(relu(agg(t1) + b1))
    gemm_mfma<128, false><<<(N + 63) / 64, 256, 0, stream>>>(x, wt1, tbuf, N);
    agg_bf16_f128<<<(N + 15) / 16, 256, 0, stream>>>(tbuf, dinv, rp, cnt, col, b1, hbuf, N);

    // layer 2: t2 = h @ bf16(W2)  (MFMA) ; z = bf16(agg(t2) + b2)
    gemm_mfma<64, true><<<(N + 63) / 64, 256, 0, stream>>>(hbuf, wt2, tbuf, N);
    agg_bf16_f64<<<(N + 31) / 32, 256, 0, stream>>>(tbuf, dinv, rp, cnt, col, b2, zbuf, N);

    // decode
    decode_kernel<<<(EL + 31) / 32, 256, 0, stream>>>(zbuf, eli, out, EL);
}